// Round 8
// baseline (277.516 us; speedup 1.0000x reference)
//
#include <hip/hip_runtime.h>
#include <hip/hip_bf16.h>

#define N_NODES 100000
#define N_EDGES 1000000
#define N_GRAPHS 2048
#define F_IN 128
#define NEG_SLOPE 0.2f
#define E_TOT (N_EDGES + N_NODES)       // edges + self-loops
#define SCAN_BLK 98                     // ceil(100000/1024)
#define GEMM_BLOCKS 1563                // ceil(100000/64)
#define HIST_BLOCKS ((E_TOT + 255) / 256)
#define NODE_BLOCKS ((N_NODES + 255) / 256)

// ---- DPP helpers (ctrl is a template constant) ------------------------------
template <int CTRL>
__device__ __forceinline__ float dpp_add(float x) {
    return x + __int_as_float(__builtin_amdgcn_update_dpp(
        0, __float_as_int(x), CTRL, 0xf, 0xf, true));
}
// sum over each 32-lane half, result broadcast to all lanes of that half
__device__ __forceinline__ float head_sum_bcast(float x) {
    x = dpp_add<0x111>(x);   // row_shr:1
    x = dpp_add<0x112>(x);   // row_shr:2
    x = dpp_add<0x114>(x);   // row_shr:4
    x = dpp_add<0x118>(x);   // row_shr:8
    x = dpp_add<0x142>(x);   // row_bcast:15
    return __int_as_float(__builtin_amdgcn_ds_swizzle(__float_as_int(x), 0x03E0));
}
// full 64-lane sum, valid in lane 63 only
__device__ __forceinline__ float full_sum64(float x) {
    x = dpp_add<0x111>(x);
    x = dpp_add<0x112>(x);
    x = dpp_add<0x114>(x);
    x = dpp_add<0x118>(x);
    x = dpp_add<0x142>(x);   // row_bcast:15
    x = dpp_add<0x143>(x);   // row_bcast:31
    return x;
}

// ========== K1: fused  xlr = x @ [W_l|W_r]  +  dst histogram (+rank) ==========
// GEMM: 64x128 tile, 256 threads as 16(ty-row-groups)x16(tx-col-groups),
// 4x8 register tile. W tile bank-swizzled: phys(col)=col+((col>>5)<<2).
__global__ __launch_bounds__(256) void k_gemm_hist(const float* __restrict__ x,
                                                   const float* __restrict__ Wl,
                                                   const float* __restrict__ Wr,
                                                   const int* __restrict__ ei,
                                                   float* __restrict__ xlr,
                                                   int* __restrict__ counts,
                                                   int* __restrict__ rank_) {
    if (blockIdx.x >= GEMM_BLOCKS) {            // -------- histogram part
        int e = (blockIdx.x - GEMM_BLOCKS) * 256 + threadIdx.x;
        if (e < E_TOT) {
            int d = (e < N_EDGES) ? ei[N_EDGES + e] : (e - N_EDGES);
            rank_[e] = atomicAdd(&counts[d], 1);    // rank within dst
        }
        return;
    }
    __shared__ float xT[8][68];                 // [k][row], +4 pad
    __shared__ float wsm[8][140];               // [k][swizzled col]
    int tid = threadIdx.x;
    int row0 = blockIdx.x * 64;
    int tx = tid & 15, ty = tid >> 4;
    int txoff = tx * 8 + ((tx >> 2) << 2);      // swizzled col base
    float acc[4][8];
#pragma unroll
    for (int i = 0; i < 4; ++i)
#pragma unroll
        for (int j = 0; j < 8; ++j) acc[i][j] = 0.f;

    for (int k0 = 0; k0 < F_IN; k0 += 8) {
        if (tid < 128) {                        // stage x: 64 rows x 8 k, transposed
            int r = tid >> 1, q = tid & 1;
            int row = row0 + r;
            float4 xv = (row < N_NODES)
                ? *(const float4*)(x + (size_t)row * F_IN + k0 + q * 4)
                : make_float4(0.f, 0.f, 0.f, 0.f);
            xT[q * 4 + 0][r] = xv.x; xT[q * 4 + 1][r] = xv.y;
            xT[q * 4 + 2][r] = xv.z; xT[q * 4 + 3][r] = xv.w;
        } else {                                // stage W: 8 k x 128 cols, swizzled
            int t = tid - 128;
#pragma unroll
            for (int u = 0; u < 2; ++u) {
                int i = t + u * 128;
                int wk = i >> 5, wc = (i & 31) * 4;
                float4 wv = (wc < 64)
                    ? *(const float4*)(Wl + (size_t)(k0 + wk) * 64 + wc)
                    : *(const float4*)(Wr + (size_t)(k0 + wk) * 64 + wc - 64);
                *(float4*)&wsm[wk][wc + ((wc >> 5) << 2)] = wv;
            }
        }
        __syncthreads();
#pragma unroll
        for (int kk = 0; kk < 8; ++kk) {
            float a[4], b[8];
            *(float4*)&a[0] = *(float4*)&xT[kk][ty * 4];
            *(float4*)&b[0] = *(float4*)&wsm[kk][txoff];
            *(float4*)&b[4] = *(float4*)&wsm[kk][txoff + 4];
#pragma unroll
            for (int i = 0; i < 4; ++i)
#pragma unroll
                for (int j = 0; j < 8; ++j) acc[i][j] += a[i] * b[j];
        }
        __syncthreads();
    }
#pragma unroll
    for (int i = 0; i < 4; ++i) {
        int r = row0 + ty * 4 + i;
        if (r < N_NODES) {
            *(float4*)(xlr + (size_t)r * 128 + tx * 8)     = make_float4(acc[i][0], acc[i][1], acc[i][2], acc[i][3]);
            *(float4*)(xlr + (size_t)r * 128 + tx * 8 + 4) = make_float4(acc[i][4], acc[i][5], acc[i][6], acc[i][7]);
        }
    }
}

// ========== K2: block-level exclusive scan of counts -> rowptr + bsum =========
__global__ __launch_bounds__(256) void k_scanA(const int* __restrict__ counts,
                                               int* __restrict__ rowptr,
                                               int* __restrict__ bsum) {
    __shared__ int sh[256];
    int t = threadIdx.x, b = blockIdx.x;
    int base = b * 1024 + t * 4;
    int v[4]; int s = 0;
#pragma unroll
    for (int i = 0; i < 4; ++i) {
        int idx = base + i;
        v[i] = (idx < N_NODES) ? counts[idx] : 0;
        s += v[i];
    }
    sh[t] = s; __syncthreads();
    for (int off = 1; off < 256; off <<= 1) {
        int xv = (t >= off) ? sh[t - off] : 0;
        __syncthreads();
        sh[t] += xv;
        __syncthreads();
    }
    int run = sh[t] - s;
    if (t == 255) bsum[b] = sh[255];
#pragma unroll
    for (int i = 0; i < 4; ++i) {
        int idx = base + i;
        if (idx < N_NODES) rowptr[idx] = run;
        run += v[i];
    }
}

// ========== K3: fused  (bsum prefix + rowptr finalize)  +  bounds =============
__global__ __launch_bounds__(256) void k_scanC_bounds(int* __restrict__ rowptr,
                                                      const int* __restrict__ bsum,
                                                      const int* __restrict__ batch,
                                                      int* __restrict__ start) {
    if (blockIdx.x < NODE_BLOCKS) {
        int i = blockIdx.x * 256 + threadIdx.x;
        int target = blockIdx.x >> 2;           // == i>>10 for whole block
        int lane = threadIdx.x & 63;
        int p = 0;
        if (lane < target)                    p  = bsum[lane];
        if (lane + 64 < target && lane + 64 < SCAN_BLK) p += bsum[lane + 64];
#pragma unroll
        for (int o = 1; o < 64; o <<= 1) p += __shfl_xor(p, o, 64);
        if (i < N_NODES) rowptr[i] += p;
        if (blockIdx.x == 0 && threadIdx.x == 0) rowptr[N_NODES] = E_TOT;
    } else {
        int i = (blockIdx.x - NODE_BLOCKS) * 256 + threadIdx.x;
        if (i >= N_NODES) return;
        int bi = batch[i];
        int bp = (i == 0) ? -1 : batch[i - 1];
        for (int g = bp + 1; g <= bi; ++g) start[g] = i;
        if (i == N_NODES - 1)
            for (int g = bi + 1; g <= N_GRAPHS; ++g) start[g] = N_NODES;
    }
}

// ========== K4: atomic-free scatter via precomputed rank ======================
__global__ __launch_bounds__(256) void k_scatter(const int* __restrict__ ei,
                                                 const int* __restrict__ rowptr,
                                                 const int* __restrict__ rank_,
                                                 int* __restrict__ sorted_src) {
    int e = blockIdx.x * 256 + threadIdx.x;
    if (e >= E_TOT) return;
    int s, d;
    if (e < N_EDGES) { s = ei[e]; d = ei[N_EDGES + e]; }
    else             { s = d = e - N_EDGES; }
    sorted_src[rowptr[d] + rank_[e]] = s;
}

// ========== K5: fused GATv2 per dst — scalarized CSR + DPP reductions =========
__global__ __launch_bounds__(256) void k_gat(const float* __restrict__ xlr,
                                             const int* __restrict__ rowptr,
                                             const int* __restrict__ sorted_src,
                                             const float* __restrict__ att,
                                             const float* __restrict__ bias,
                                             const float* __restrict__ w_rel,
                                             const float* __restrict__ w_root,
                                             float* __restrict__ hfeat,
                                             float* __restrict__ tbuf,
                                             float* __restrict__ rbuf) {
    int lane = threadIdx.x & 63;
    int du = __builtin_amdgcn_readfirstlane(blockIdx.x * 4 + (threadIdx.x >> 6));
    if (du >= N_NODES) return;                  // wave-uniform exit
    float xr_l  = xlr[(size_t)du * 128 + 64 + lane];
    float att_l = att[lane];
    int j0 = __builtin_amdgcn_readfirstlane(rowptr[du]);
    int j1 = __builtin_amdgcn_readfirstlane(rowptr[du + 1]);   // >= j0+1 (self-loop)
    float m = -1e30f, wsum = 0.f, acc = 0.f;
    for (int jc = j0; jc < j1; jc += 8) {
        int n = j1 - jc;                        // valid edges this chunk (may exceed 8)
        int jj = jc + (lane & 7);
        if (jj > j1 - 1) jj = j1 - 1;
        int sv = sorted_src[jj];                // edge i's src sits in lane i (i<8)
        float p[8], xv[8];
#pragma unroll
        for (int i = 0; i < 8; ++i) {           // SGPR-based gathers
            int s = __builtin_amdgcn_readlane(sv, i);
            const float* ps = xlr + (size_t)(unsigned)s * 128;
            xv[i] = ps[lane];
        }
#pragma unroll
        for (int i = 0; i < 8; ++i) {
            float v = xv[i] + xr_l;
            v = (v > 0.f) ? v : NEG_SLOPE * v;
            p[i] = v * att_l;
        }
#pragma unroll
        for (int i = 0; i < 8; ++i)             // per-head 32-lane dot, DPP
            p[i] = head_sum_bcast(p[i]);
#pragma unroll
        for (int i = 0; i < 8; ++i)
            if (i >= n) p[i] = -1e30f;          // mask tail -> w = 0
        float mc = p[0];
#pragma unroll
        for (int i = 1; i < 8; ++i) mc = fmaxf(mc, p[i]);
        float cws = 0.f, cacc = 0.f;
#pragma unroll
        for (int i = 0; i < 8; ++i) {
            float w = __expf(p[i] - mc);
            cws += w;
            cacc += w * xv[i];
        }
        float mnew = fmaxf(m, mc);
        float fo = __expf(m - mnew), fn = __expf(mc - mnew);
        wsum = wsum * fo + cws * fn;
        acc  = acc  * fo + cacc * fn;
        m = mnew;
    }
    float h = acc / wsum + bias[lane];
    hfeat[(size_t)du * 64 + lane] = h;
    float a = full_sum64(h * w_rel[lane]);
    float b = full_sum64(h * w_root[lane]);
    if (lane == 63) { tbuf[du] = a; rbuf[du] = b; }
}

// ========== K6: fused score + per-graph softmax-pool (block per graph) ========
__global__ __launch_bounds__(256) void k_pool(const int* __restrict__ rowptr,
                                              const int* __restrict__ sorted_src,
                                              const float* __restrict__ t,
                                              const float* __restrict__ r,
                                              const float* __restrict__ b_score,
                                              float* __restrict__ score,
                                              const float* __restrict__ h,
                                              const int* __restrict__ start,
                                              float* __restrict__ out) {
    __shared__ float sh[4];
    __shared__ float shacc[4][64];
    int g = blockIdx.x;
    int tid = threadIdx.x, w = tid >> 6, lane = tid & 63;
    int n0 = start[g], n1 = start[g + 1];
    int cnt = n1 - n0;
    if (cnt <= 0) { if (tid < 64) out[(size_t)g * 64 + tid] = 0.f; return; }
    float bsc = b_score[0];
    // --- phase 1: scores (GraphConv aggr via sorted CSR), 4-way ILP
    for (int i = n0 + tid; i < n1; i += 256) {
        int jj0 = rowptr[i], jj1 = rowptr[i + 1];
        float sum = 0.f;
        int j = jj0;
        for (; j + 4 <= jj1; j += 4) {
            int s0 = sorted_src[j], s1 = sorted_src[j + 1];
            int s2 = sorted_src[j + 2], s3 = sorted_src[j + 3];
            sum += t[s0] + t[s1] + t[s2] + t[s3];
        }
        for (; j < jj1; ++j) sum += t[sorted_src[j]];
        score[i] = sum - t[i] + r[i] + bsc;     // self-loop in list once -> subtract
    }
    __syncthreads();
    // --- phase 2: softmax over scores + weighted pool
    float m = -1e30f;
    for (int i = n0 + tid; i < n1; i += 256) m = fmaxf(m, score[i]);
#pragma unroll
    for (int o = 32; o; o >>= 1) m = fmaxf(m, __shfl_xor(m, o, 64));
    if (lane == 0) sh[w] = m;
    __syncthreads();
    m = fmaxf(fmaxf(sh[0], sh[1]), fmaxf(sh[2], sh[3]));
    float ssum = 0.f;
    for (int i = n0 + tid; i < n1; i += 256) ssum += __expf(score[i] - m);
#pragma unroll
    for (int o = 32; o; o >>= 1) ssum += __shfl_xor(ssum, o, 64);
    __syncthreads();
    if (lane == 0) sh[w] = ssum;
    __syncthreads();
    ssum = sh[0] + sh[1] + sh[2] + sh[3];
    float acc = 0.f;
    for (int i = n0 + w; i < n1; i += 4)
        acc += __expf(score[i] - m) * h[(size_t)i * 64 + lane];
    shacc[w][lane] = acc;
    __syncthreads();
    if (w == 0) {
        float tot = shacc[0][lane] + shacc[1][lane] + shacc[2][lane] + shacc[3][lane];
        out[(size_t)g * 64 + lane] = tot * (1.f + 1.f / (float)cnt) / ssum;
    }
}

extern "C" void kernel_launch(void* const* d_in, const int* in_sizes, int n_in,
                              void* d_out, int out_size, void* d_ws, size_t ws_size,
                              hipStream_t stream) {
    const float* x      = (const float*)d_in[0];
    const int*   ei     = (const int*)d_in[1];
    const int*   batch  = (const int*)d_in[2];
    const float* Wl     = (const float*)d_in[3];
    const float* Wr     = (const float*)d_in[4];
    const float* att    = (const float*)d_in[5];
    const float* bias   = (const float*)d_in[6];
    const float* w_rel  = (const float*)d_in[7];
    const float* w_root = (const float*)d_in[8];
    const float* b_sc   = (const float*)d_in[9];

    char* ws = (char*)d_ws;
    size_t off = 0;
    auto alloc = [&](size_t bytes) { void* p = ws + off; off += (bytes + 255) & ~255ull; return p; };
    float* xlr        = (float*)alloc((size_t)N_NODES * 128 * 4);
    float* hfeat      = (float*)alloc((size_t)N_NODES * 64 * 4);
    int*   sorted_src = (int*)  alloc((size_t)E_TOT * 4);
    int*   rank_      = (int*)  alloc((size_t)E_TOT * 4);
    int*   counts     = (int*)  alloc((size_t)N_NODES * 4);
    int*   rowptr     = (int*)  alloc((size_t)(N_NODES + 1) * 4);
    int*   bsum       = (int*)  alloc((size_t)SCAN_BLK * 4);
    float* tbuf       = (float*)alloc((size_t)N_NODES * 4);
    float* rbuf       = (float*)alloc((size_t)N_NODES * 4);
    float* score      = (float*)alloc((size_t)N_NODES * 4);
    int*   start      = (int*)  alloc((size_t)(N_GRAPHS + 1) * 4);

    (void)hipMemsetAsync(counts, 0, (size_t)N_NODES * 4, stream);

    k_gemm_hist   <<<GEMM_BLOCKS + HIST_BLOCKS, 256, 0, stream>>>(x, Wl, Wr, ei, xlr, counts, rank_);
    k_scanA       <<<SCAN_BLK, 256, 0, stream>>>(counts, rowptr, bsum);
    k_scanC_bounds<<<NODE_BLOCKS * 2, 256, 0, stream>>>(rowptr, bsum, batch, start);
    k_scatter     <<<(E_TOT + 255) / 256, 256, 0, stream>>>(ei, rowptr, rank_, sorted_src);
    k_gat         <<<(N_NODES + 3) / 4, 256, 0, stream>>>(xlr, rowptr, sorted_src, att, bias,
                                                          w_rel, w_root, hfeat, tbuf, rbuf);
    k_pool        <<<N_GRAPHS, 256, 0, stream>>>(rowptr, sorted_src, tbuf, rbuf, b_sc,
                                                 score, hfeat, start, (float*)d_out);
}

// Round 9
// 248.995 us; speedup vs baseline: 1.1145x; 1.1145x over previous
//
#include <hip/hip_runtime.h>
#include <hip/hip_bf16.h>

#define N_NODES 100000
#define N_EDGES 1000000
#define N_GRAPHS 2048
#define F_IN 128
#define NEG_SLOPE 0.2f
#define E_TOT (N_EDGES + N_NODES)       // edges + self-loops
#define SCAN_BLK 98                     // ceil(100000/1024)
#define GEMM_BLOCKS 782                 // ceil(100000/128)
#define HIST_BLOCKS ((E_TOT + 255) / 256)
#define NODE_BLOCKS ((N_NODES + 255) / 256)

typedef short  bf16x8 __attribute__((ext_vector_type(8)));
typedef float  f32x16 __attribute__((ext_vector_type(16)));

__device__ __forceinline__ short f2bf(float f) {      // RNE f32 -> bf16 bits
    unsigned u = __float_as_uint(f);
    unsigned r = (u + 0x7fffu + ((u >> 16) & 1u)) >> 16;
    return (short)r;
}
__device__ __forceinline__ float bf2f(short h) {
    return __uint_as_float(((unsigned)(unsigned short)h) << 16);
}

// ---- DPP helpers (ctrl is a template constant) ------------------------------
template <int CTRL>
__device__ __forceinline__ float dpp_add(float x) {
    return x + __int_as_float(__builtin_amdgcn_update_dpp(
        0, __float_as_int(x), CTRL, 0xf, 0xf, true));
}
__device__ __forceinline__ float head_sum_bcast(float x) {
    x = dpp_add<0x111>(x);   // row_shr:1
    x = dpp_add<0x112>(x);   // row_shr:2
    x = dpp_add<0x114>(x);   // row_shr:4
    x = dpp_add<0x118>(x);   // row_shr:8
    x = dpp_add<0x142>(x);   // row_bcast:15
    return __int_as_float(__builtin_amdgcn_ds_swizzle(__float_as_int(x), 0x03E0));
}
__device__ __forceinline__ float full_sum64(float x) {
    x = dpp_add<0x111>(x);
    x = dpp_add<0x112>(x);
    x = dpp_add<0x114>(x);
    x = dpp_add<0x118>(x);
    x = dpp_add<0x142>(x);   // row_bcast:15
    x = dpp_add<0x143>(x);   // row_bcast:31
    return x;
}

// ========== K1: fused  xlr = x @ [W_l|W_r] (split-bf16 MFMA)  +  histogram ====
// 128 rows/block, 4 waves x 32 rows. W transposed+hi/lo-split staged once in
// LDS (1 barrier); A-frags straight from global with in-register cvt.
// acc = xhi*whi + xhi*wlo + xlo*whi  (lo*lo dropped, ~1e-5 rel err).
__global__ __launch_bounds__(256) void k_gemm_hist(const float* __restrict__ x,
                                                   const float* __restrict__ Wl,
                                                   const float* __restrict__ Wr,
                                                   const int* __restrict__ ei,
                                                   float* __restrict__ xlr,
                                                   int* __restrict__ counts,
                                                   int* __restrict__ rank_) {
    if (blockIdx.x >= GEMM_BLOCKS) {            // -------- histogram part
        int e = (blockIdx.x - GEMM_BLOCKS) * 256 + threadIdx.x;
        if (e < E_TOT) {
            int d = (e < N_EDGES) ? ei[N_EDGES + e] : (e - N_EDGES);
            rank_[e] = atomicAdd(&counts[d], 1);    // rank within dst
        }
        return;
    }
    __shared__ short wt[2][128][136];           // [hi/lo][n][k], +8 bf16 pad
    int tid = threadIdx.x;
    {   // ---- stage W transposed + split (once) ----
        int k  = tid >> 1;                      // 0..127
        int cq = tid & 1;                       // 0: cols 0-63 (Wl), 1: 64-127 (Wr)
        const float* Wsrc = cq ? Wr : Wl;
#pragma unroll
        for (int u = 0; u < 16; ++u) {
            int c0 = u * 4;
            float4 wv = *(const float4*)(Wsrc + (size_t)k * 64 + c0);
            float vv[4] = {wv.x, wv.y, wv.z, wv.w};
#pragma unroll
            for (int q = 0; q < 4; ++q) {
                int c = cq * 64 + c0 + q;
                short hi = f2bf(vv[q]);
                wt[0][c][k] = hi;
                wt[1][c][k] = f2bf(vv[q] - bf2f(hi));
            }
        }
    }
    __syncthreads();
    // ---- MFMA: wave w -> rows row0 + w*32 .. +31, 4 col-tiles of 32
    int lane = tid & 63, w = tid >> 6;
    int m = lane & 31, half = lane >> 5;
    int row = blockIdx.x * 128 + w * 32 + m;
    bool rv = row < N_NODES;
    const float* xrow = x + (size_t)(rv ? row : 0) * F_IN;
    f32x16 acc[4];
#pragma unroll
    for (int t = 0; t < 4; ++t)
#pragma unroll
        for (int i = 0; i < 16; ++i) acc[t][i] = 0.f;

#pragma unroll
    for (int kt = 0; kt < 8; ++kt) {            // K=16 steps
        int kb = kt * 16 + half * 8;            // this lane's k-base
        float4 xa = rv ? *(const float4*)(xrow + kb)
                       : make_float4(0.f, 0.f, 0.f, 0.f);
        float4 xb = rv ? *(const float4*)(xrow + kb + 4)
                       : make_float4(0.f, 0.f, 0.f, 0.f);
        float xs[8] = {xa.x, xa.y, xa.z, xa.w, xb.x, xb.y, xb.z, xb.w};
        bf16x8 ahi, alo;
#pragma unroll
        for (int j = 0; j < 8; ++j) {
            short hi = f2bf(xs[j]);
            ahi[j] = hi;
            alo[j] = f2bf(xs[j] - bf2f(hi));
        }
#pragma unroll
        for (int t = 0; t < 4; ++t) {
            int n = t * 32 + m;
            bf16x8 bhi = *(const bf16x8*)&wt[0][n][kb];
            bf16x8 blo = *(const bf16x8*)&wt[1][n][kb];
            acc[t] = __builtin_amdgcn_mfma_f32_32x32x16_bf16(ahi, bhi, acc[t], 0, 0, 0);
            acc[t] = __builtin_amdgcn_mfma_f32_32x32x16_bf16(ahi, blo, acc[t], 0, 0, 0);
            acc[t] = __builtin_amdgcn_mfma_f32_32x32x16_bf16(alo, bhi, acc[t], 0, 0, 0);
        }
    }
    // ---- store: D[row=(reg&3)+8*(reg>>2)+4*half][col=t*32+m]
    int r0 = blockIdx.x * 128 + w * 32 + 4 * half;
#pragma unroll
    for (int t = 0; t < 4; ++t)
#pragma unroll
        for (int reg = 0; reg < 16; ++reg) {
            int rr = r0 + (reg & 3) + 8 * (reg >> 2);
            if (rr < N_NODES)
                xlr[(size_t)rr * 128 + t * 32 + m] = acc[t][reg];
        }
}

// ========== K2: block-level exclusive scan of counts -> rowptr + bsum =========
__global__ __launch_bounds__(256) void k_scanA(const int* __restrict__ counts,
                                               int* __restrict__ rowptr,
                                               int* __restrict__ bsum) {
    __shared__ int sh[256];
    int t = threadIdx.x, b = blockIdx.x;
    int base = b * 1024 + t * 4;
    int v[4]; int s = 0;
#pragma unroll
    for (int i = 0; i < 4; ++i) {
        int idx = base + i;
        v[i] = (idx < N_NODES) ? counts[idx] : 0;
        s += v[i];
    }
    sh[t] = s; __syncthreads();
    for (int off = 1; off < 256; off <<= 1) {
        int xv = (t >= off) ? sh[t - off] : 0;
        __syncthreads();
        sh[t] += xv;
        __syncthreads();
    }
    int run = sh[t] - s;
    if (t == 255) bsum[b] = sh[255];
#pragma unroll
    for (int i = 0; i < 4; ++i) {
        int idx = base + i;
        if (idx < N_NODES) rowptr[idx] = run;
        run += v[i];
    }
}

// ========== K3: fused  (bsum prefix + rowptr finalize)  +  bounds =============
__global__ __launch_bounds__(256) void k_scanC_bounds(int* __restrict__ rowptr,
                                                      const int* __restrict__ bsum,
                                                      const int* __restrict__ batch,
                                                      int* __restrict__ start) {
    if (blockIdx.x < NODE_BLOCKS) {
        int i = blockIdx.x * 256 + threadIdx.x;
        int target = blockIdx.x >> 2;           // == i>>10 for whole block
        int lane = threadIdx.x & 63;
        int p = 0;
        if (lane < target)                    p  = bsum[lane];
        if (lane + 64 < target && lane + 64 < SCAN_BLK) p += bsum[lane + 64];
#pragma unroll
        for (int o = 1; o < 64; o <<= 1) p += __shfl_xor(p, o, 64);
        if (i < N_NODES) rowptr[i] += p;
        if (blockIdx.x == 0 && threadIdx.x == 0) rowptr[N_NODES] = E_TOT;
    } else {
        int i = (blockIdx.x - NODE_BLOCKS) * 256 + threadIdx.x;
        if (i >= N_NODES) return;
        int bi = batch[i];
        int bp = (i == 0) ? -1 : batch[i - 1];
        for (int g = bp + 1; g <= bi; ++g) start[g] = i;
        if (i == N_NODES - 1)
            for (int g = bi + 1; g <= N_GRAPHS; ++g) start[g] = N_NODES;
    }
}

// ========== K4: atomic-free scatter via precomputed rank ======================
__global__ __launch_bounds__(256) void k_scatter(const int* __restrict__ ei,
                                                 const int* __restrict__ rowptr,
                                                 const int* __restrict__ rank_,
                                                 int* __restrict__ sorted_src) {
    int e = blockIdx.x * 256 + threadIdx.x;
    if (e >= E_TOT) return;
    int s, d;
    if (e < N_EDGES) { s = ei[e]; d = ei[N_EDGES + e]; }
    else             { s = d = e - N_EDGES; }
    sorted_src[rowptr[d] + rank_[e]] = s;
}

// ========== K5: fused GATv2 per dst — scalarized CSR + DPP reductions =========
__global__ __launch_bounds__(256) void k_gat(const float* __restrict__ xlr,
                                             const int* __restrict__ rowptr,
                                             const int* __restrict__ sorted_src,
                                             const float* __restrict__ att,
                                             const float* __restrict__ bias,
                                             const float* __restrict__ w_rel,
                                             const float* __restrict__ w_root,
                                             float* __restrict__ hfeat,
                                             float* __restrict__ tbuf,
                                             float* __restrict__ rbuf) {
    int lane = threadIdx.x & 63;
    int du = __builtin_amdgcn_readfirstlane(blockIdx.x * 4 + (threadIdx.x >> 6));
    if (du >= N_NODES) return;                  // wave-uniform exit
    float xr_l  = xlr[(size_t)du * 128 + 64 + lane];
    float att_l = att[lane];
    int j0 = __builtin_amdgcn_readfirstlane(rowptr[du]);
    int j1 = __builtin_amdgcn_readfirstlane(rowptr[du + 1]);   // >= j0+1 (self-loop)
    float m = -1e30f, wsum = 0.f, acc = 0.f;
    for (int jc = j0; jc < j1; jc += 8) {
        int n = j1 - jc;                        // valid edges this chunk (may exceed 8)
        int jj = jc + (lane & 7);
        if (jj > j1 - 1) jj = j1 - 1;
        int sv = sorted_src[jj];                // edge i's src sits in lane i (i<8)
        float p[8], xv[8];
#pragma unroll
        for (int i = 0; i < 8; ++i) {           // SGPR-based gathers
            int s = __builtin_amdgcn_readlane(sv, i);
            const float* ps = xlr + (size_t)(unsigned)s * 128;
            xv[i] = ps[lane];
        }
#pragma unroll
        for (int i = 0; i < 8; ++i) {
            float v = xv[i] + xr_l;
            v = (v > 0.f) ? v : NEG_SLOPE * v;
            p[i] = v * att_l;
        }
#pragma unroll
        for (int i = 0; i < 8; ++i)             // per-head 32-lane dot, DPP
            p[i] = head_sum_bcast(p[i]);
#pragma unroll
        for (int i = 0; i < 8; ++i)
            if (i >= n) p[i] = -1e30f;          // mask tail -> w = 0
        float mc = p[0];
#pragma unroll
        for (int i = 1; i < 8; ++i) mc = fmaxf(mc, p[i]);
        float cws = 0.f, cacc = 0.f;
#pragma unroll
        for (int i = 0; i < 8; ++i) {
            float wgt = __expf(p[i] - mc);
            cws += wgt;
            cacc += wgt * xv[i];
        }
        float mnew = fmaxf(m, mc);
        float fo = __expf(m - mnew), fn = __expf(mc - mnew);
        wsum = wsum * fo + cws * fn;
        acc  = acc  * fo + cacc * fn;
        m = mnew;
    }
    float h = acc / wsum + bias[lane];
    hfeat[(size_t)du * 64 + lane] = h;
    float a = full_sum64(h * w_rel[lane]);
    float b = full_sum64(h * w_root[lane]);
    if (lane == 63) { tbuf[du] = a; rbuf[du] = b; }
}

// ========== K6: fused score + per-graph softmax-pool (block per graph) ========
__global__ __launch_bounds__(256) void k_pool(const int* __restrict__ rowptr,
                                              const int* __restrict__ sorted_src,
                                              const float* __restrict__ t,
                                              const float* __restrict__ r,
                                              const float* __restrict__ b_score,
                                              float* __restrict__ score,
                                              const float* __restrict__ h,
                                              const int* __restrict__ start,
                                              float* __restrict__ out) {
    __shared__ float sh[4];
    __shared__ float shacc[4][64];
    int g = blockIdx.x;
    int tid = threadIdx.x, w = tid >> 6, lane = tid & 63;
    int n0 = start[g], n1 = start[g + 1];
    int cnt = n1 - n0;
    if (cnt <= 0) { if (tid < 64) out[(size_t)g * 64 + tid] = 0.f; return; }
    float bsc = b_score[0];
    // --- phase 1: scores (GraphConv aggr via sorted CSR), 4-way ILP
    for (int i = n0 + tid; i < n1; i += 256) {
        int jj0 = rowptr[i], jj1 = rowptr[i + 1];
        float sum = 0.f;
        int j = jj0;
        for (; j + 4 <= jj1; j += 4) {
            int s0 = sorted_src[j], s1 = sorted_src[j + 1];
            int s2 = sorted_src[j + 2], s3 = sorted_src[j + 3];
            sum += t[s0] + t[s1] + t[s2] + t[s3];
        }
        for (; j < jj1; ++j) sum += t[sorted_src[j]];
        score[i] = sum - t[i] + r[i] + bsc;     // self-loop in list once -> subtract
    }
    __syncthreads();
    // --- phase 2: softmax over scores + weighted pool
    float m = -1e30f;
    for (int i = n0 + tid; i < n1; i += 256) m = fmaxf(m, score[i]);
#pragma unroll
    for (int o = 32; o; o >>= 1) m = fmaxf(m, __shfl_xor(m, o, 64));
    if (lane == 0) sh[w] = m;
    __syncthreads();
    m = fmaxf(fmaxf(sh[0], sh[1]), fmaxf(sh[2], sh[3]));
    float ssum = 0.f;
    for (int i = n0 + tid; i < n1; i += 256) ssum += __expf(score[i] - m);
#pragma unroll
    for (int o = 32; o; o >>= 1) ssum += __shfl_xor(ssum, o, 64);
    __syncthreads();
    if (lane == 0) sh[w] = ssum;
    __syncthreads();
    ssum = sh[0] + sh[1] + sh[2] + sh[3];
    float acc = 0.f;
    for (int i = n0 + w; i < n1; i += 4)
        acc += __expf(score[i] - m) * h[(size_t)i * 64 + lane];
    shacc[w][lane] = acc;
    __syncthreads();
    if (w == 0) {
        float tot = shacc[0][lane] + shacc[1][lane] + shacc[2][lane] + shacc[3][lane];
        out[(size_t)g * 64 + lane] = tot * (1.f + 1.f / (float)cnt) / ssum;
    }
}

extern "C" void kernel_launch(void* const* d_in, const int* in_sizes, int n_in,
                              void* d_out, int out_size, void* d_ws, size_t ws_size,
                              hipStream_t stream) {
    const float* x      = (const float*)d_in[0];
    const int*   ei     = (const int*)d_in[1];
    const int*   batch  = (const int*)d_in[2];
    const float* Wl     = (const float*)d_in[3];
    const float* Wr     = (const float*)d_in[4];
    const float* att    = (const float*)d_in[5];
    const float* bias   = (const float*)d_in[6];
    const float* w_rel  = (const float*)d_in[7];
    const float* w_root = (const float*)d_in[8];
    const float* b_sc   = (const float*)d_in[9];

    char* ws = (char*)d_ws;
    size_t off = 0;
    auto alloc = [&](size_t bytes) { void* p = ws + off; off += (bytes + 255) & ~255ull; return p; };
    float* xlr        = (float*)alloc((size_t)N_NODES * 128 * 4);
    float* hfeat      = (float*)alloc((size_t)N_NODES * 64 * 4);
    int*   sorted_src = (int*)  alloc((size_t)E_TOT * 4);
    int*   rank_      = (int*)  alloc((size_t)E_TOT * 4);
    int*   counts     = (int*)  alloc((size_t)N_NODES * 4);
    int*   rowptr     = (int*)  alloc((size_t)(N_NODES + 1) * 4);
    int*   bsum       = (int*)  alloc((size_t)SCAN_BLK * 4);
    float* tbuf       = (float*)alloc((size_t)N_NODES * 4);
    float* rbuf       = (float*)alloc((size_t)N_NODES * 4);
    float* score      = (float*)alloc((size_t)N_NODES * 4);
    int*   start      = (int*)  alloc((size_t)(N_GRAPHS + 1) * 4);

    (void)hipMemsetAsync(counts, 0, (size_t)N_NODES * 4, stream);

    k_gemm_hist   <<<GEMM_BLOCKS + HIST_BLOCKS, 256, 0, stream>>>(x, Wl, Wr, ei, xlr, counts, rank_);
    k_scanA       <<<SCAN_BLK, 256, 0, stream>>>(counts, rowptr, bsum);
    k_scanC_bounds<<<NODE_BLOCKS * 2, 256, 0, stream>>>(rowptr, bsum, batch, start);
    k_scatter     <<<(E_TOT + 255) / 256, 256, 0, stream>>>(ei, rowptr, rank_, sorted_src);
    k_gat         <<<(N_NODES + 3) / 4, 256, 0, stream>>>(xlr, rowptr, sorted_src, att, bias,
                                                          w_rel, w_root, hfeat, tbuf, rbuf);
    k_pool        <<<N_GRAPHS, 256, 0, stream>>>(rowptr, sorted_src, tbuf, rbuf, b_sc,
                                                 score, hfeat, start, (float*)d_out);
}